// Round 4
// baseline (3874.042 us; speedup 1.0000x reference)
//
#include <hip/hip_runtime.h>

typedef unsigned short u16;
typedef __bf16 bf16x8 __attribute__((ext_vector_type(8)));
typedef float floatx4 __attribute__((ext_vector_type(4)));
typedef u16 u16x8 __attribute__((ext_vector_type(8)));

#define D_MODEL 2048
#define S_LEN   2048
#define BATCH   2
#define NHEAD   32
#define GROUPS  8
#define HEAD_DIM 64
#define KV_DIM  512

__device__ __forceinline__ float bf2f(u16 h) {
  unsigned int u = ((unsigned int)h) << 16;
  return __builtin_bit_cast(float, u);
}
__device__ __forceinline__ u16 f2bf(float f) {
  unsigned int u = __builtin_bit_cast(unsigned int, f);
  u += 0x7fffu + ((u >> 16) & 1u);
  return (u16)(u >> 16);
}

// C = A @ W^T + bias.  W fp32 [N][K], bias fp32 [N].
// A_F32: A is fp32 [M][K] (converted to bf16 during staging); else A is bf16.
// C_F32: C stored fp32; else bf16.
// M%128==0, N%128==0, K%32==0.
template<bool A_F32, bool C_F32>
__global__ __launch_bounds__(256, 2)
void gemm_bt_bias(const void* __restrict__ Av, const float* __restrict__ W,
                  const float* __restrict__ bias, void* __restrict__ Cv,
                  int K, int ldc)
{
  __shared__ __align__(16) u16 As[128 * 32];
  __shared__ __align__(16) u16 Bs[128 * 32];
  const int t = threadIdx.x;
  const int w = t >> 6, l = t & 63;
  const int lr = l & 15, lq = l >> 4;
  const int wm = (w >> 1) * 64, wn = (w & 1) * 64;
  const long bm = (long)blockIdx.x * 128;
  const long bn = (long)blockIdx.y * 128;

  floatx4 acc[4][4] = {};

  // thread t stages row (t>>2), k-elems (t&3)*8..+7 ; +64 rows for the second instr
  const long aoff = (bm + (t >> 2)) * (long)K + (t & 3) * 8;
  const float* af0; const u16* ab0;
  if (A_F32) af0 = (const float*)Av + aoff; else ab0 = (const u16*)Av + aoff;
  const float* b0 = W + (bn + (t >> 2)) * (long)K + (t & 3) * 8;
  const float* b1 = b0 + 64L * K;

  for (int k0 = 0; k0 < K; k0 += 32) {
    u16x8 ra0, ra1, rb0, rb1;
    if (A_F32) {
      floatx4 x0 = *(const floatx4*)(af0 + k0);
      floatx4 x1 = *(const floatx4*)(af0 + k0 + 4);
      floatx4 y0 = *(const floatx4*)(af0 + 64L * K + k0);
      floatx4 y1 = *(const floatx4*)(af0 + 64L * K + k0 + 4);
#pragma unroll
      for (int j = 0; j < 4; ++j) {
        ra0[j] = f2bf(x0[j]); ra0[4 + j] = f2bf(x1[j]);
        ra1[j] = f2bf(y0[j]); ra1[4 + j] = f2bf(y1[j]);
      }
    } else {
      ra0 = *(const u16x8*)(ab0 + k0);
      ra1 = *(const u16x8*)(ab0 + 64L * K + k0);
    }
    {
      floatx4 x0 = *(const floatx4*)(b0 + k0);
      floatx4 x1 = *(const floatx4*)(b0 + k0 + 4);
      floatx4 y0 = *(const floatx4*)(b1 + k0);
      floatx4 y1 = *(const floatx4*)(b1 + k0 + 4);
#pragma unroll
      for (int j = 0; j < 4; ++j) {
        rb0[j] = f2bf(x0[j]); rb0[4 + j] = f2bf(x1[j]);
        rb1[j] = f2bf(y0[j]); rb1[4 + j] = f2bf(y1[j]);
      }
    }
    __syncthreads();                       // prev iteration's LDS reads done
    *(u16x8*)&As[t * 8]        = ra0;
    *(u16x8*)&As[2048 + t * 8] = ra1;
    *(u16x8*)&Bs[t * 8]        = rb0;
    *(u16x8*)&Bs[2048 + t * 8] = rb1;
    __syncthreads();                       // LDS writes visible

    bf16x8 av[4], bv[4];
#pragma unroll
    for (int i = 0; i < 4; ++i)
      av[i] = *(const bf16x8*)(As + (wm + i * 16 + lr) * 32 + lq * 8);
#pragma unroll
    for (int j = 0; j < 4; ++j)
      bv[j] = *(const bf16x8*)(Bs + (wn + j * 16 + lr) * 32 + lq * 8);
#pragma unroll
    for (int i = 0; i < 4; ++i)
#pragma unroll
      for (int j = 0; j < 4; ++j)
        acc[i][j] = __builtin_amdgcn_mfma_f32_16x16x32_bf16(av[i], bv[j], acc[i][j], 0, 0, 0);
  }

  float bb[4];
#pragma unroll
  for (int j = 0; j < 4; ++j)
    bb[j] = bias[bn + wn + j * 16 + lr];
#pragma unroll
  for (int i = 0; i < 4; ++i) {
#pragma unroll
    for (int rr = 0; rr < 4; ++rr) {
      long row = bm + wm + i * 16 + lq * 4 + rr;
      long cidx = row * (long)ldc + bn + wn + lr;
#pragma unroll
      for (int j = 0; j < 4; ++j) {
        float v = acc[i][j][rr] + bb[j];
        if (C_F32) ((float*)Cv)[cidx + j * 16] = v;
        else       ((u16*)Cv)[cidx + j * 16] = f2bf(v);
      }
    }
  }
}

// In-place rotate-half RoPE on Q [B*S, 2048] (32 heads) and K [B*S, 512] (8 groups), bf16
__global__ __launch_bounds__(256)
void rope_kernel(u16* __restrict__ Q, u16* __restrict__ Kc)
{
  const int bs = blockIdx.x;
  const int s = bs & (S_LEN - 1);
  const int t = threadIdx.x;
  u16* qrow = Q + (long)bs * D_MODEL;
#pragma unroll
  for (int i = 0; i < 4; ++i) {
    int p = t + i * 256;
    int hh = p >> 5, d = p & 31;
    float theta = __expf(-(float)d * 0.28782313662425574f); // ln(10000)/32
    float sn, cs;
    sincosf((float)s * theta, &sn, &cs);
    int i0 = hh * 64 + d;
    float x0 = bf2f(qrow[i0]), x1 = bf2f(qrow[i0 + 32]);
    qrow[i0]      = f2bf(x0 * cs - x1 * sn);
    qrow[i0 + 32] = f2bf(x1 * cs + x0 * sn);
  }
  u16* krow = Kc + (long)bs * KV_DIM;
  {
    int g = t >> 5, d = t & 31;
    float theta = __expf(-(float)d * 0.28782313662425574f);
    float sn, cs;
    sincosf((float)s * theta, &sn, &cs);
    int i0 = g * 64 + d;
    float x0 = bf2f(krow[i0]), x1 = bf2f(krow[i0 + 32]);
    krow[i0]      = f2bf(x0 * cs - x1 * sn);
    krow[i0 + 32] = f2bf(x1 * cs + x0 * sn);
  }
}

// Scalar flash-style causal GQA (bf16 in/out). 1 wave/block; thread = one q-row.
__global__ __launch_bounds__(64)
void gqa_attn_scalar(const u16* Q, const u16* __restrict__ Kc,
                     const u16* __restrict__ Vc, u16* O)
{
  __shared__ float Ksf[64 * 65];
  __shared__ float Vsf[64 * 65];

  const int qt = blockIdx.x;
  const int bh = blockIdx.y;
  const int b = bh >> 5, h = bh & 31, g = h >> 2;
  const int lane = threadIdx.x;          // 0..63
  const int r = qt * 64 + lane;

  const u16* Qrow  = Q + ((long)b * S_LEN + r) * D_MODEL + h * HEAD_DIM;
  const u16* Kbase = Kc + ((long)b * S_LEN) * KV_DIM + g * HEAD_DIM;
  const u16* Vbase = Vc + ((long)b * S_LEN) * KV_DIM + g * HEAD_DIM;

  float q[64], o[64];
#pragma unroll
  for (int i = 0; i < 8; ++i) {
    u16x8 v = *(const u16x8*)(Qrow + i * 8);
#pragma unroll
    for (int j = 0; j < 8; ++j) q[i * 8 + j] = bf2f(v[j]);
  }
#pragma unroll
  for (int d = 0; d < 64; ++d) o[d] = 0.f;
  float m = -1e30f, l = 0.f;

  for (int kt = 0; kt <= qt; ++kt) {
    __syncthreads();
    const u16* krow = Kbase + (long)(kt * 64 + lane) * KV_DIM;
    const u16* vrow = Vbase + (long)(kt * 64 + lane) * KV_DIM;
#pragma unroll
    for (int i = 0; i < 8; ++i) {
      u16x8 kv = *(const u16x8*)(krow + i * 8);
      u16x8 vv = *(const u16x8*)(vrow + i * 8);
#pragma unroll
      for (int j = 0; j < 8; ++j) {
        Ksf[lane * 65 + i * 8 + j] = bf2f(kv[j]);
        Vsf[lane * 65 + i * 8 + j] = bf2f(vv[j]);
      }
    }
    __syncthreads();

    const int kmax = (kt == qt) ? (lane + 1) : 64;
    for (int kc = 0; kc < kmax; ++kc) {
      float s = 0.f;
#pragma unroll
      for (int d = 0; d < 64; ++d) s += q[d] * Ksf[kc * 65 + d];
      s *= 0.125f;
      if (s > m) {
        float alpha = __expf(m - s);
        m = s;
        l *= alpha;
#pragma unroll
        for (int d = 0; d < 64; ++d) o[d] *= alpha;
      }
      float p = __expf(s - m);
      l += p;
#pragma unroll
      for (int d = 0; d < 64; ++d) o[d] += p * Vsf[kc * 65 + d];
    }
  }

  float inv = 1.f / l;
  u16* Orow = O + ((long)b * S_LEN + r) * D_MODEL + h * HEAD_DIM;
#pragma unroll
  for (int d = 0; d < 64; ++d) Orow[d] = f2bf(o[d] * inv);
}

extern "C" void kernel_launch(void* const* d_in, const int* in_sizes, int n_in,
                              void* d_out, int out_size, void* d_ws, size_t ws_size,
                              hipStream_t stream)
{
  const float* x  = (const float*)d_in[0];
  const float* Wq = (const float*)d_in[1];
  const float* bq = (const float*)d_in[2];
  const float* Wk = (const float*)d_in[3];
  const float* bk = (const float*)d_in[4];
  const float* Wv = (const float*)d_in[5];
  const float* bv = (const float*)d_in[6];
  const float* Wo = (const float*)d_in[7];
  const float* bo = (const float*)d_in[8];
  float* out = (float*)d_out;

  u16* Qb = (u16*)d_ws;                        // [4096,2048] bf16
  u16* Kb = Qb + (size_t)4096 * 2048;          // [4096,512]
  u16* Vb = Kb + (size_t)4096 * 512;           // [4096,512]
  u16* AO = Qb;                                // attention out aliases Q (row-private)

  const int M = BATCH * S_LEN;                 // 4096
  dim3 blk(256);
  gemm_bt_bias<true, false><<<dim3(M / 128, D_MODEL / 128), blk, 0, stream>>>(x, Wq, bq, Qb, D_MODEL, D_MODEL);
  gemm_bt_bias<true, false><<<dim3(M / 128, KV_DIM / 128),  blk, 0, stream>>>(x, Wk, bk, Kb, D_MODEL, KV_DIM);
  gemm_bt_bias<true, false><<<dim3(M / 128, KV_DIM / 128),  blk, 0, stream>>>(x, Wv, bv, Vb, D_MODEL, KV_DIM);
  rope_kernel<<<dim3(M), blk, 0, stream>>>(Qb, Kb);
  gqa_attn_scalar<<<dim3(S_LEN / 64, BATCH * NHEAD), dim3(64), 0, stream>>>(Qb, Kb, Vb, AO);
  gemm_bt_bias<false, true><<<dim3(M / 128, D_MODEL / 128), blk, 0, stream>>>(AO, Wo, bo, out, D_MODEL, D_MODEL);
}

// Round 5
// 773.235 us; speedup vs baseline: 5.0102x; 5.0102x over previous
//
#include <hip/hip_runtime.h>

typedef unsigned short u16;
typedef __bf16 bf16x8 __attribute__((ext_vector_type(8)));
typedef float floatx4 __attribute__((ext_vector_type(4)));
typedef u16 u16x8 __attribute__((ext_vector_type(8)));

#define D_MODEL 2048
#define S_LEN   2048
#define BATCH   2
#define NHEAD   32
#define GROUPS  8
#define HEAD_DIM 64
#define KV_DIM  512

__device__ __forceinline__ float bf2f(u16 h) {
  unsigned int u = ((unsigned int)h) << 16;
  return __builtin_bit_cast(float, u);
}
__device__ __forceinline__ u16 f2bf(float f) {
  unsigned int u = __builtin_bit_cast(unsigned int, f);
  u += 0x7fffu + ((u >> 16) & 1u);
  return (u16)(u >> 16);
}

// C = A @ W^T + bias.  W fp32 [N][K], bias fp32 [N].
// A_F32: A is fp32 (converted to bf16 during staging); else A is bf16.
// C_F32: C stored fp32; else bf16.  M%128==0, N%128==0, K%32==0.
template<bool A_F32, bool C_F32>
__global__ __launch_bounds__(256, 2)
void gemm_bt_bias(const void* __restrict__ Av, const float* __restrict__ W,
                  const float* __restrict__ bias, void* __restrict__ Cv,
                  int K, int ldc)
{
  __shared__ __align__(16) u16 As[128 * 32];
  __shared__ __align__(16) u16 Bs[128 * 32];
  const int t = threadIdx.x;
  const int w = t >> 6, l = t & 63;
  const int lr = l & 15, lq = l >> 4;
  const int wm = (w >> 1) * 64, wn = (w & 1) * 64;
  const long bm = (long)blockIdx.x * 128;
  const long bn = (long)blockIdx.y * 128;

  floatx4 acc[4][4] = {};

  const long aoff = (bm + (t >> 2)) * (long)K + (t & 3) * 8;
  const float* af0; const u16* ab0;
  if (A_F32) af0 = (const float*)Av + aoff; else ab0 = (const u16*)Av + aoff;
  const float* b0 = W + (bn + (t >> 2)) * (long)K + (t & 3) * 8;
  const float* b1 = b0 + 64L * K;

  for (int k0 = 0; k0 < K; k0 += 32) {
    u16x8 ra0, ra1, rb0, rb1;
    if (A_F32) {
      floatx4 x0 = *(const floatx4*)(af0 + k0);
      floatx4 x1 = *(const floatx4*)(af0 + k0 + 4);
      floatx4 y0 = *(const floatx4*)(af0 + 64L * K + k0);
      floatx4 y1 = *(const floatx4*)(af0 + 64L * K + k0 + 4);
#pragma unroll
      for (int j = 0; j < 4; ++j) {
        ra0[j] = f2bf(x0[j]); ra0[4 + j] = f2bf(x1[j]);
        ra1[j] = f2bf(y0[j]); ra1[4 + j] = f2bf(y1[j]);
      }
    } else {
      ra0 = *(const u16x8*)(ab0 + k0);
      ra1 = *(const u16x8*)(ab0 + 64L * K + k0);
    }
    {
      floatx4 x0 = *(const floatx4*)(b0 + k0);
      floatx4 x1 = *(const floatx4*)(b0 + k0 + 4);
      floatx4 y0 = *(const floatx4*)(b1 + k0);
      floatx4 y1 = *(const floatx4*)(b1 + k0 + 4);
#pragma unroll
      for (int j = 0; j < 4; ++j) {
        rb0[j] = f2bf(x0[j]); rb0[4 + j] = f2bf(x1[j]);
        rb1[j] = f2bf(y0[j]); rb1[4 + j] = f2bf(y1[j]);
      }
    }
    __syncthreads();
    *(u16x8*)&As[t * 8]        = ra0;
    *(u16x8*)&As[2048 + t * 8] = ra1;
    *(u16x8*)&Bs[t * 8]        = rb0;
    *(u16x8*)&Bs[2048 + t * 8] = rb1;
    __syncthreads();

    bf16x8 av[4], bv[4];
#pragma unroll
    for (int i = 0; i < 4; ++i)
      av[i] = *(const bf16x8*)(As + (wm + i * 16 + lr) * 32 + lq * 8);
#pragma unroll
    for (int j = 0; j < 4; ++j)
      bv[j] = *(const bf16x8*)(Bs + (wn + j * 16 + lr) * 32 + lq * 8);
#pragma unroll
    for (int i = 0; i < 4; ++i)
#pragma unroll
      for (int j = 0; j < 4; ++j)
        acc[i][j] = __builtin_amdgcn_mfma_f32_16x16x32_bf16(av[i], bv[j], acc[i][j], 0, 0, 0);
  }

  float bb[4];
#pragma unroll
  for (int j = 0; j < 4; ++j)
    bb[j] = bias[bn + wn + j * 16 + lr];
#pragma unroll
  for (int i = 0; i < 4; ++i) {
#pragma unroll
    for (int rr = 0; rr < 4; ++rr) {
      long row = bm + wm + i * 16 + lq * 4 + rr;
      long cidx = row * (long)ldc + bn + wn + lr;
#pragma unroll
      for (int j = 0; j < 4; ++j) {
        float v = acc[i][j][rr] + bb[j];
        if (C_F32) ((float*)Cv)[cidx + j * 16] = v;
        else       ((u16*)Cv)[cidx + j * 16] = f2bf(v);
      }
    }
  }
}

// In-place rotate-half RoPE on Q [B*S, 2048] (32 heads) and K [B*S, 512] (8 groups), bf16
__global__ __launch_bounds__(256)
void rope_kernel(u16* __restrict__ Q, u16* __restrict__ Kc)
{
  const int bs = blockIdx.x;
  const int s = bs & (S_LEN - 1);
  const int t = threadIdx.x;
  u16* qrow = Q + (long)bs * D_MODEL;
#pragma unroll
  for (int i = 0; i < 4; ++i) {
    int p = t + i * 256;
    int hh = p >> 5, d = p & 31;
    float theta = __expf(-(float)d * 0.28782313662425574f); // ln(10000)/32
    float sn, cs;
    sincosf((float)s * theta, &sn, &cs);
    int i0 = hh * 64 + d;
    float x0 = bf2f(qrow[i0]), x1 = bf2f(qrow[i0 + 32]);
    qrow[i0]      = f2bf(x0 * cs - x1 * sn);
    qrow[i0 + 32] = f2bf(x1 * cs + x0 * sn);
  }
  u16* krow = Kc + (long)bs * KV_DIM;
  {
    int g = t >> 5, d = t & 31;
    float theta = __expf(-(float)d * 0.28782313662425574f);
    float sn, cs;
    sincosf((float)s * theta, &sn, &cs);
    int i0 = g * 64 + d;
    float x0 = bf2f(krow[i0]), x1 = bf2f(krow[i0 + 32]);
    krow[i0]      = f2bf(x0 * cs - x1 * sn);
    krow[i0 + 32] = f2bf(x1 * cs + x0 * sn);
  }
}

// MFMA flash-style causal GQA. grid = (S/64, B*NHEAD), block = 256 (4 waves x 16 q-rows).
// O may alias Q (block-diagonal access; Q frags register-resident before O stores).
__global__ __launch_bounds__(256, 2)
void gqa_attn(const u16* Q, const u16* __restrict__ Kc,
              const u16* __restrict__ Vc, u16* O)
{
  __shared__ __align__(16) u16 Ks[64 * 72];      // K[kcol][d], padded rows
  __shared__ __align__(16) u16 Vts[64 * 72];     // V^T: [d][kcol]
  __shared__ __align__(16) u16 Ps[4][16 * 72];   // per-wave P tile [q][kcol]

  const int qt = blockIdx.x;
  const int bh = blockIdx.y;
  const int b = bh >> 5, h = bh & 31, g = h >> 2;

  const u16* Qp = Q + ((long)b * S_LEN) * D_MODEL + h * HEAD_DIM;
  const u16* Kp = Kc + ((long)b * S_LEN) * KV_DIM + g * HEAD_DIM;
  const u16* Vp = Vc + ((long)b * S_LEN) * KV_DIM + g * HEAD_DIM;
  u16* Op = O + ((long)b * S_LEN) * D_MODEL + h * HEAD_DIM;

  const int t = threadIdx.x;
  const int w = t >> 6, l = t & 63;
  const int lr = l & 15, lq = l >> 4;

  bf16x8 qf[2];
  {
    const u16* qrow = Qp + (long)(qt * 64 + w * 16 + lr) * D_MODEL;
    qf[0] = *(const bf16x8*)(qrow + lq * 8);
    qf[1] = *(const bf16x8*)(qrow + 32 + lq * 8);
  }

  floatx4 o[4] = {};
  float m_i[4] = {-1e30f, -1e30f, -1e30f, -1e30f};
  float l_i[4] = {0.f, 0.f, 0.f, 0.f};

  const int r64 = t & 63;
  const int dc = (t >> 6) * 16;

  for (int kt = 0; kt <= qt; ++kt) {
    { // stage K tile and transposed V tile
      const u16* krow = Kp + (long)(kt * 64 + r64) * KV_DIM + dc;
      u16x8 k0 = *(const u16x8*)(krow);
      u16x8 k1 = *(const u16x8*)(krow + 8);
      *(u16x8*)&Ks[r64 * 72 + dc] = k0;
      *(u16x8*)&Ks[r64 * 72 + dc + 8] = k1;
      const u16* vrow = Vp + (long)(kt * 64 + r64) * KV_DIM + dc;
      u16x8 v0 = *(const u16x8*)(vrow);
      u16x8 v1 = *(const u16x8*)(vrow + 8);
#pragma unroll
      for (int i = 0; i < 8; ++i) Vts[(dc + i) * 72 + r64] = v0[i];
#pragma unroll
      for (int i = 0; i < 8; ++i) Vts[(dc + 8 + i) * 72 + r64] = v1[i];
    }
    __syncthreads();

    // S = Q K^T for this wave's 16 q-rows x 64 k-cols
    floatx4 sc[4];
#pragma unroll
    for (int j = 0; j < 4; ++j) {
      bf16x8 kf0 = *(const bf16x8*)&Ks[(j * 16 + lr) * 72 + lq * 8];
      bf16x8 kf1 = *(const bf16x8*)&Ks[(j * 16 + lr) * 72 + 32 + lq * 8];
      floatx4 z = {};
      z = __builtin_amdgcn_mfma_f32_16x16x32_bf16(qf[0], kf0, z, 0, 0, 0);
      z = __builtin_amdgcn_mfma_f32_16x16x32_bf16(qf[1], kf1, z, 0, 0, 0);
      sc[j] = z;
    }
    if (kt == qt) {
#pragma unroll
      for (int j = 0; j < 4; ++j)
#pragma unroll
        for (int rr = 0; rr < 4; ++rr) {
          int col = j * 16 + lr, row = w * 16 + lq * 4 + rr;
          sc[j][rr] = (col > row) ? -1e30f : sc[j][rr] * 0.125f;
        }
    } else {
#pragma unroll
      for (int j = 0; j < 4; ++j)
#pragma unroll
        for (int rr = 0; rr < 4; ++rr) sc[j][rr] *= 0.125f;
    }

    // online softmax per q-row (row rr lives on the 16 lanes sharing lq)
#pragma unroll
    for (int rr = 0; rr < 4; ++rr) {
      float mx = fmaxf(fmaxf(sc[0][rr], sc[1][rr]), fmaxf(sc[2][rr], sc[3][rr]));
      mx = fmaxf(mx, __shfl_xor(mx, 1));
      mx = fmaxf(mx, __shfl_xor(mx, 2));
      mx = fmaxf(mx, __shfl_xor(mx, 4));
      mx = fmaxf(mx, __shfl_xor(mx, 8));
      float mnew = fmaxf(m_i[rr], mx);
      float alpha = __expf(m_i[rr] - mnew);
      float ps = 0.f;
#pragma unroll
      for (int j = 0; j < 4; ++j) {
        float p = __expf(sc[j][rr] - mnew);
        sc[j][rr] = p;
        ps += p;
      }
      ps += __shfl_xor(ps, 1);
      ps += __shfl_xor(ps, 2);
      ps += __shfl_xor(ps, 4);
      ps += __shfl_xor(ps, 8);
      l_i[rr] = l_i[rr] * alpha + ps;
      m_i[rr] = mnew;
      o[0][rr] *= alpha; o[1][rr] *= alpha; o[2][rr] *= alpha; o[3][rr] *= alpha;
#pragma unroll
      for (int j = 0; j < 4; ++j)
        Ps[w][(lq * 4 + rr) * 72 + j * 16 + lr] = f2bf(sc[j][rr]);
    }
    __syncthreads();   // guarantee P-store -> P-read ordering (LDS write/read, cross-lane)

    // O += P V   (P via LDS: C-layout -> A-layout)
    {
      bf16x8 pa0 = *(const bf16x8*)&Ps[w][lr * 72 + lq * 8];
      bf16x8 pa1 = *(const bf16x8*)&Ps[w][lr * 72 + 32 + lq * 8];
#pragma unroll
      for (int j = 0; j < 4; ++j) {
        bf16x8 vb0 = *(const bf16x8*)&Vts[(j * 16 + lr) * 72 + lq * 8];
        bf16x8 vb1 = *(const bf16x8*)&Vts[(j * 16 + lr) * 72 + 32 + lq * 8];
        o[j] = __builtin_amdgcn_mfma_f32_16x16x32_bf16(pa0, vb0, o[j], 0, 0, 0);
        o[j] = __builtin_amdgcn_mfma_f32_16x16x32_bf16(pa1, vb1, o[j], 0, 0, 0);
      }
    }
    __syncthreads();
  }

#pragma unroll
  for (int rr = 0; rr < 4; ++rr) {
    float inv = 1.f / l_i[rr];
    long row = qt * 64 + w * 16 + lq * 4 + rr;
    u16* op = Op + row * (long)D_MODEL + lr;
#pragma unroll
    for (int j = 0; j < 4; ++j)
      op[j * 16] = f2bf(o[j][rr] * inv);
  }
}

extern "C" void kernel_launch(void* const* d_in, const int* in_sizes, int n_in,
                              void* d_out, int out_size, void* d_ws, size_t ws_size,
                              hipStream_t stream)
{
  const float* x  = (const float*)d_in[0];
  const float* Wq = (const float*)d_in[1];
  const float* bq = (const float*)d_in[2];
  const float* Wk = (const float*)d_in[3];
  const float* bk = (const float*)d_in[4];
  const float* Wv = (const float*)d_in[5];
  const float* bv = (const float*)d_in[6];
  const float* Wo = (const float*)d_in[7];
  const float* bo = (const float*)d_in[8];
  float* out = (float*)d_out;

  u16* Qb = (u16*)d_ws;                        // [4096,2048] bf16
  u16* Kb = Qb + (size_t)4096 * 2048;          // [4096,512]
  u16* Vb = Kb + (size_t)4096 * 512;           // [4096,512]
  u16* AO = Qb;                                // attention out aliases Q (block-diagonal safe)

  const int M = BATCH * S_LEN;                 // 4096
  dim3 blk(256);
  gemm_bt_bias<true, false><<<dim3(M / 128, D_MODEL / 128), blk, 0, stream>>>(x, Wq, bq, Qb, D_MODEL, D_MODEL);
  gemm_bt_bias<true, false><<<dim3(M / 128, KV_DIM / 128),  blk, 0, stream>>>(x, Wk, bk, Kb, D_MODEL, KV_DIM);
  gemm_bt_bias<true, false><<<dim3(M / 128, KV_DIM / 128),  blk, 0, stream>>>(x, Wv, bv, Vb, D_MODEL, KV_DIM);
  rope_kernel<<<dim3(M), blk, 0, stream>>>(Qb, Kb);
  gqa_attn<<<dim3(S_LEN / 64, BATCH * NHEAD), blk, 0, stream>>>(Qb, Kb, Vb, AO);
  gemm_bt_bias<false, true><<<dim3(M / 128, D_MODEL / 128), blk, 0, stream>>>(AO, Wo, bo, out, D_MODEL, D_MODEL);
}

// Round 6
// 532.331 us; speedup vs baseline: 7.2775x; 1.4525x over previous
//
#include <hip/hip_runtime.h>

typedef unsigned short u16;
typedef __bf16 bf16x8 __attribute__((ext_vector_type(8)));
typedef float floatx4 __attribute__((ext_vector_type(4)));
typedef u16 u16x8 __attribute__((ext_vector_type(8)));

#define D_MODEL 2048
#define S_LEN   2048
#define BATCH   2
#define NHEAD   32
#define GROUPS  8
#define HEAD_DIM 64
#define KV_DIM  512

__device__ __forceinline__ float bf2f(u16 h) {
  unsigned int u = ((unsigned int)h) << 16;
  return __builtin_bit_cast(float, u);
}
__device__ __forceinline__ u16 f2bf(float f) {
  unsigned int u = __builtin_bit_cast(unsigned int, f);
  u += 0x7fffu + ((u >> 16) & 1u);
  return (u16)(u >> 16);
}

#define GLD_LDS(gp, lp) \
  __builtin_amdgcn_global_load_lds((__attribute__((address_space(1))) void*)(gp), \
                                   (__attribute__((address_space(3))) void*)(lp), 16, 0, 0)

// Fused fp32 -> bf16 conversion for 5 tensors. grid = (4096, 5), 8 elems/thread.
__global__ __launch_bounds__(256)
void cvt5_f32_bf16(const float* s0, const float* s1, const float* s2,
                   const float* s3, const float* s4,
                   u16* d0, u16* d1, u16* d2, u16* d3, u16* d4,
                   int n0, int n1, int n2, int n3, int n4)
{
  const float* s; u16* d; int n;
  switch (blockIdx.y) {
    case 0: s = s0; d = d0; n = n0; break;
    case 1: s = s1; d = d1; n = n1; break;
    case 2: s = s2; d = d2; n = n2; break;
    case 3: s = s3; d = d3; n = n3; break;
    default: s = s4; d = d4; n = n4; break;
  }
  long i = ((long)blockIdx.x * 256 + threadIdx.x) * 8;
  if (i >= n) return;
  floatx4 a = *(const floatx4*)(s + i);
  floatx4 b = *(const floatx4*)(s + i + 4);
  u16x8 r;
#pragma unroll
  for (int j = 0; j < 4; ++j) { r[j] = f2bf(a[j]); r[4 + j] = f2bf(b[j]); }
  *(u16x8*)(d + i) = r;
}

// C = A @ W^T + bias.  A bf16 [M][K], W bf16 [N][K], bias fp32 [N].
// C_F32: C stored fp32; else bf16.  M%128==0, N%128==0, K%32==0.
// m97-style: 128x128 tile, BK=32, async global_load_lds width=16.
template<bool C_F32>
__global__ __launch_bounds__(256, 2)
void gemm_bt_bias(const u16* __restrict__ A, const u16* __restrict__ W,
                  const float* __restrict__ bias, void* __restrict__ Cv,
                  int K, int ldc)
{
  __shared__ __align__(16) u16 As[128 * 32];
  __shared__ __align__(16) u16 Bs[128 * 32];
  const int t = threadIdx.x;
  const int w = t >> 6, l = t & 63;
  const int lr = l & 15, lq = l >> 4;
  const int wm = (w >> 1) * 64, wn = (w & 1) * 64;
  const long bm = (long)blockIdx.x * 128;
  const long bn = (long)blockIdx.y * 128;

  floatx4 acc[4][4] = {};

  // staging: chunk c covers row c>>2, k-elems (c&3)*8..+7; instr0: c=t, instr1: c=t+256
  const u16* a0 = A + (bm + (t >> 2)) * (long)K + (t & 3) * 8;
  const u16* a1 = a0 + 64L * K;
  const u16* b0 = W + (bn + (t >> 2)) * (long)K + (t & 3) * 8;
  const u16* b1 = b0 + 64L * K;
  u16* As0 = As + w * 512;          // wave-uniform LDS bases (lane lands at +lane*16B)
  u16* As1 = As + 2048 + w * 512;
  u16* Bs0 = Bs + w * 512;
  u16* Bs1 = Bs + 2048 + w * 512;

  for (int k0 = 0; k0 < K; k0 += 32) {
    GLD_LDS(a0 + k0, As0);
    GLD_LDS(a1 + k0, As1);
    GLD_LDS(b0 + k0, Bs0);
    GLD_LDS(b1 + k0, Bs1);
    __syncthreads();

    bf16x8 av[4], bv[4];
#pragma unroll
    for (int i = 0; i < 4; ++i)
      av[i] = *(const bf16x8*)(As + (wm + i * 16 + lr) * 32 + lq * 8);
#pragma unroll
    for (int j = 0; j < 4; ++j)
      bv[j] = *(const bf16x8*)(Bs + (wn + j * 16 + lr) * 32 + lq * 8);
#pragma unroll
    for (int i = 0; i < 4; ++i)
#pragma unroll
      for (int j = 0; j < 4; ++j)
        acc[i][j] = __builtin_amdgcn_mfma_f32_16x16x32_bf16(av[i], bv[j], acc[i][j], 0, 0, 0);
    __syncthreads();
  }

  float bb[4];
#pragma unroll
  for (int j = 0; j < 4; ++j)
    bb[j] = bias[bn + wn + j * 16 + lr];
#pragma unroll
  for (int i = 0; i < 4; ++i) {
#pragma unroll
    for (int rr = 0; rr < 4; ++rr) {
      long row = bm + wm + i * 16 + lq * 4 + rr;
      long cidx = row * (long)ldc + bn + wn + lr;
#pragma unroll
      for (int j = 0; j < 4; ++j) {
        float v = acc[i][j][rr] + bb[j];
        if (C_F32) ((float*)Cv)[cidx + j * 16] = v;
        else       ((u16*)Cv)[cidx + j * 16] = f2bf(v);
      }
    }
  }
}

// In-place rotate-half RoPE on Q [B*S, 2048] (32 heads) and K [B*S, 512] (8 groups), bf16
__global__ __launch_bounds__(256)
void rope_kernel(u16* __restrict__ Q, u16* __restrict__ Kc)
{
  const int bs = blockIdx.x;
  const int s = bs & (S_LEN - 1);
  const int t = threadIdx.x;
  u16* qrow = Q + (long)bs * D_MODEL;
#pragma unroll
  for (int i = 0; i < 4; ++i) {
    int p = t + i * 256;
    int hh = p >> 5, d = p & 31;
    float theta = __expf(-(float)d * 0.28782313662425574f); // ln(10000)/32
    float sn, cs;
    sincosf((float)s * theta, &sn, &cs);
    int i0 = hh * 64 + d;
    float x0 = bf2f(qrow[i0]), x1 = bf2f(qrow[i0 + 32]);
    qrow[i0]      = f2bf(x0 * cs - x1 * sn);
    qrow[i0 + 32] = f2bf(x1 * cs + x0 * sn);
  }
  u16* krow = Kc + (long)bs * KV_DIM;
  {
    int g = t >> 5, d = t & 31;
    float theta = __expf(-(float)d * 0.28782313662425574f);
    float sn, cs;
    sincosf((float)s * theta, &sn, &cs);
    int i0 = g * 64 + d;
    float x0 = bf2f(krow[i0]), x1 = bf2f(krow[i0 + 32]);
    krow[i0]      = f2bf(x0 * cs - x1 * sn);
    krow[i0 + 32] = f2bf(x1 * cs + x0 * sn);
  }
}

// MFMA flash-style causal GQA. grid = (S/64, B*NHEAD), block = 256 (4 waves x 16 q-rows).
// O may alias Q (block-diagonal access; Q frags register-resident before O stores).
__global__ __launch_bounds__(256, 2)
void gqa_attn(const u16* Q, const u16* __restrict__ Kc,
              const u16* __restrict__ Vc, u16* O)
{
  __shared__ __align__(16) u16 Ks[64 * 72];      // K[kcol][d], padded rows
  __shared__ __align__(16) u16 Vts[64 * 72];     // V^T: [d][kcol]
  __shared__ __align__(16) u16 Ps[4][16 * 72];   // per-wave P tile [q][kcol]

  const int qt = blockIdx.x;
  const int bh = blockIdx.y;
  const int b = bh >> 5, h = bh & 31, g = h >> 2;

  const u16* Qp = Q + ((long)b * S_LEN) * D_MODEL + h * HEAD_DIM;
  const u16* Kp = Kc + ((long)b * S_LEN) * KV_DIM + g * HEAD_DIM;
  const u16* Vp = Vc + ((long)b * S_LEN) * KV_DIM + g * HEAD_DIM;
  u16* Op = O + ((long)b * S_LEN) * D_MODEL + h * HEAD_DIM;

  const int t = threadIdx.x;
  const int w = t >> 6, l = t & 63;
  const int lr = l & 15, lq = l >> 4;

  bf16x8 qf[2];
  {
    const u16* qrow = Qp + (long)(qt * 64 + w * 16 + lr) * D_MODEL;
    qf[0] = *(const bf16x8*)(qrow + lq * 8);
    qf[1] = *(const bf16x8*)(qrow + 32 + lq * 8);
  }

  floatx4 o[4] = {};
  float m_i[4] = {-1e30f, -1e30f, -1e30f, -1e30f};
  float l_i[4] = {0.f, 0.f, 0.f, 0.f};

  const int r64 = t & 63;
  const int dc = (t >> 6) * 16;

  for (int kt = 0; kt <= qt; ++kt) {
    { // stage K tile and transposed V tile
      const u16* krow = Kp + (long)(kt * 64 + r64) * KV_DIM + dc;
      u16x8 k0 = *(const u16x8*)(krow);
      u16x8 k1 = *(const u16x8*)(krow + 8);
      *(u16x8*)&Ks[r64 * 72 + dc] = k0;
      *(u16x8*)&Ks[r64 * 72 + dc + 8] = k1;
      const u16* vrow = Vp + (long)(kt * 64 + r64) * KV_DIM + dc;
      u16x8 v0 = *(const u16x8*)(vrow);
      u16x8 v1 = *(const u16x8*)(vrow + 8);
#pragma unroll
      for (int i = 0; i < 8; ++i) Vts[(dc + i) * 72 + r64] = v0[i];
#pragma unroll
      for (int i = 0; i < 8; ++i) Vts[(dc + 8 + i) * 72 + r64] = v1[i];
    }
    __syncthreads();

    // S = Q K^T for this wave's 16 q-rows x 64 k-cols
    floatx4 sc[4];
#pragma unroll
    for (int j = 0; j < 4; ++j) {
      bf16x8 kf0 = *(const bf16x8*)&Ks[(j * 16 + lr) * 72 + lq * 8];
      bf16x8 kf1 = *(const bf16x8*)&Ks[(j * 16 + lr) * 72 + 32 + lq * 8];
      floatx4 z = {};
      z = __builtin_amdgcn_mfma_f32_16x16x32_bf16(qf[0], kf0, z, 0, 0, 0);
      z = __builtin_amdgcn_mfma_f32_16x16x32_bf16(qf[1], kf1, z, 0, 0, 0);
      sc[j] = z;
    }
    if (kt == qt) {
#pragma unroll
      for (int j = 0; j < 4; ++j)
#pragma unroll
        for (int rr = 0; rr < 4; ++rr) {
          int col = j * 16 + lr, row = w * 16 + lq * 4 + rr;
          sc[j][rr] = (col > row) ? -1e30f : sc[j][rr] * 0.125f;
        }
    } else {
#pragma unroll
      for (int j = 0; j < 4; ++j)
#pragma unroll
        for (int rr = 0; rr < 4; ++rr) sc[j][rr] *= 0.125f;
    }

    // online softmax per q-row (row rr lives on the 16 lanes sharing lq)
#pragma unroll
    for (int rr = 0; rr < 4; ++rr) {
      float mx = fmaxf(fmaxf(sc[0][rr], sc[1][rr]), fmaxf(sc[2][rr], sc[3][rr]));
      mx = fmaxf(mx, __shfl_xor(mx, 1));
      mx = fmaxf(mx, __shfl_xor(mx, 2));
      mx = fmaxf(mx, __shfl_xor(mx, 4));
      mx = fmaxf(mx, __shfl_xor(mx, 8));
      float mnew = fmaxf(m_i[rr], mx);
      float alpha = __expf(m_i[rr] - mnew);
      float ps = 0.f;
#pragma unroll
      for (int j = 0; j < 4; ++j) {
        float p = __expf(sc[j][rr] - mnew);
        sc[j][rr] = p;
        ps += p;
      }
      ps += __shfl_xor(ps, 1);
      ps += __shfl_xor(ps, 2);
      ps += __shfl_xor(ps, 4);
      ps += __shfl_xor(ps, 8);
      l_i[rr] = l_i[rr] * alpha + ps;
      m_i[rr] = mnew;
      o[0][rr] *= alpha; o[1][rr] *= alpha; o[2][rr] *= alpha; o[3][rr] *= alpha;
#pragma unroll
      for (int j = 0; j < 4; ++j)
        Ps[w][(lq * 4 + rr) * 72 + j * 16 + lr] = f2bf(sc[j][rr]);
    }
    __syncthreads();   // P-store -> P-read ordering

    // O += P V   (P via LDS: C-layout -> A-layout)
    {
      bf16x8 pa0 = *(const bf16x8*)&Ps[w][lr * 72 + lq * 8];
      bf16x8 pa1 = *(const bf16x8*)&Ps[w][lr * 72 + 32 + lq * 8];
#pragma unroll
      for (int j = 0; j < 4; ++j) {
        bf16x8 vb0 = *(const bf16x8*)&Vts[(j * 16 + lr) * 72 + lq * 8];
        bf16x8 vb1 = *(const bf16x8*)&Vts[(j * 16 + lr) * 72 + 32 + lq * 8];
        o[j] = __builtin_amdgcn_mfma_f32_16x16x32_bf16(pa0, vb0, o[j], 0, 0, 0);
        o[j] = __builtin_amdgcn_mfma_f32_16x16x32_bf16(pa1, vb1, o[j], 0, 0, 0);
      }
    }
    __syncthreads();
  }

#pragma unroll
  for (int rr = 0; rr < 4; ++rr) {
    float inv = 1.f / l_i[rr];
    long row = qt * 64 + w * 16 + lq * 4 + rr;
    u16* op = Op + row * (long)D_MODEL + lr;
#pragma unroll
    for (int j = 0; j < 4; ++j)
      op[j * 16] = f2bf(o[j][rr] * inv);
  }
}

extern "C" void kernel_launch(void* const* d_in, const int* in_sizes, int n_in,
                              void* d_out, int out_size, void* d_ws, size_t ws_size,
                              hipStream_t stream)
{
  const float* x  = (const float*)d_in[0];
  const float* Wq = (const float*)d_in[1];
  const float* bq = (const float*)d_in[2];
  const float* Wk = (const float*)d_in[3];
  const float* bk = (const float*)d_in[4];
  const float* Wv = (const float*)d_in[5];
  const float* bv = (const float*)d_in[6];
  const float* Wo = (const float*)d_in[7];
  const float* bo = (const float*)d_in[8];
  float* out = (float*)d_out;

  const int Sx  = BATCH * S_LEN * D_MODEL;     // 8388608
  const int SWq = D_MODEL * D_MODEL;           // 4194304
  const int SWk = KV_DIM * D_MODEL;            // 1048576
  const int SWv = KV_DIM * D_MODEL;            // 1048576
  const int SWo = D_MODEL * D_MODEL;           // 4194304

  u16* xb  = (u16*)d_ws;
  u16* Wqb = xb  + Sx;
  u16* Wkb = Wqb + SWq;
  u16* Wvb = Wkb + SWk;
  u16* Wob = Wvb + SWv;
  u16* Qb  = Wob + SWo;                        // [4096,2048] bf16
  u16* Kb  = Qb + (size_t)4096 * 2048;         // [4096,512]
  u16* Vb  = Kb + (size_t)4096 * 512;          // [4096,512]
  u16* AO  = Qb;                               // attention out aliases Q

  const int M = BATCH * S_LEN;                 // 4096
  dim3 blk(256);
  cvt5_f32_bf16<<<dim3(4096, 5), blk, 0, stream>>>(x, Wq, Wk, Wv, Wo,
                                                   xb, Wqb, Wkb, Wvb, Wob,
                                                   Sx, SWq, SWk, SWv, SWo);
  gemm_bt_bias<false><<<dim3(M / 128, D_MODEL / 128), blk, 0, stream>>>(xb, Wqb, bq, Qb, D_MODEL, D_MODEL);
  gemm_bt_bias<false><<<dim3(M / 128, KV_DIM / 128),  blk, 0, stream>>>(xb, Wkb, bk, Kb, D_MODEL, KV_DIM);
  gemm_bt_bias<false><<<dim3(M / 128, KV_DIM / 128),  blk, 0, stream>>>(xb, Wvb, bv, Vb, D_MODEL, KV_DIM);
  rope_kernel<<<dim3(M), blk, 0, stream>>>(Qb, Kb);
  gqa_attn<<<dim3(S_LEN / 64, BATCH * NHEAD), blk, 0, stream>>>(Qb, Kb, Vb, AO);
  gemm_bt_bias<true><<<dim3(M / 128, D_MODEL / 128), blk, 0, stream>>>(AO, Wob, bo, out, D_MODEL, D_MODEL);
}